// Round 3
// baseline (548.430 us; speedup 1.0000x reference)
//
#include <hip/hip_runtime.h>
#include <math.h>

typedef float f2 __attribute__((ext_vector_type(2)));
typedef float f4 __attribute__((ext_vector_type(4)));

#define DD 160
#define HH 160
#define WW 160
#define BB 4
#define KK 11
#define RAD 5
#define TH 32                     // H tile
#define TW 16                     // W tile
#define DCH 20                    // output planes per block along D
#define NPLANES (DCH + 2 * RAD)   // 30
#define NDCH (DD / DCH)           // 8
#define HALO_H (TH + 2 * RAD)     // 42
#define HALO_W (TW + 2 * RAD)     // 26
#define SW 28                     // s row stride: SW/4=7 odd -> b128 groups spread uniformly
#define TS 20                     // tmp row stride: 8 consecutive rows -> 4 words/bank exactly

struct GaussW { float g[KK]; };

__global__ __launch_bounds__(256)
void ssim3d_kernel(const float* __restrict__ img1,
                   const float* __restrict__ img2,
                   float* __restrict__ out, GaussW gw)
{
    __shared__ float s1[HALO_H * SW];
    __shared__ float s2[HALO_H * SW];
    __shared__ float tmp[5][HALO_H * TS];
    __shared__ float wsum[4];

    const int tid = threadIdx.x;      // 256 threads = 4 waves
    const int xc  = tid & 7;          // output col pair (2xc, 2xc+1)
    const int ty  = tid >> 3;         // output row 0..31

    const int blk = blockIdx.x;
    const int bw = blk % 10;
    const int bh = (blk / 10) % 5;
    const int bd = (blk / 50) % NDCH;
    const int bb = blk / (50 * NDCH);

    const int oh0 = bh * TH, ow0 = bw * TW, od0 = bd * DCH;
    const float* base1 = img1 + (size_t)bb * DD * HH * WW;
    const float* base2 = img2 + (size_t)bb * DD * HH * WW;

    float g[KK];
#pragma unroll
    for (int i = 0; i < KK; ++i) g[i] = gw.g[i];

    // D-ring: slot i -> output plane emitted i planes from now (f2 = 2 W-cols)
    f2 a1[KK], a2[KK], a11[KK], a22[KK], a12[KK];
#pragma unroll
    for (int i = 0; i < KK; ++i) { a1[i]=0.f; a2[i]=0.f; a11[i]=0.f; a22[i]=0.f; a12[i]=0.f; }

    const bool inb_hw = (oh0 >= RAD) && (oh0 + TH + RAD <= HH) &&
                        (ow0 >= RAD) && (ow0 + TW + RAD <= WW);

    f2 lsum = 0.f;

    for (int p = 0; p < NPLANES; ++p) {
        const int d = od0 - RAD + p;
        const bool dval = (d >= 0) && (d < DD);   // block-uniform

        if (dval) {
            // ---- stage A: load 42x26 halo of this plane into LDS ----
            const size_t pb = (size_t)d * HH * WW;
            if (inb_hw) {
                const float* q1 = base1 + pb + (size_t)(oh0 - RAD) * WW + (ow0 - RAD);
                const float* q2 = base2 + pb + (size_t)(oh0 - RAD) * WW + (ow0 - RAD);
                for (int e = tid; e < HALO_H * HALO_W; e += 256) {
                    int r = e / HALO_W, c = e - r * HALO_W;
                    s1[r * SW + c] = q1[r * WW + c];
                    s2[r * SW + c] = q2[r * WW + c];
                }
            } else {
                for (int e = tid; e < HALO_H * HALO_W; e += 256) {
                    int r = e / HALO_W, c = e - r * HALO_W;
                    int ih = oh0 - RAD + r, iw = ow0 - RAD + c;
                    float v1 = 0.f, v2 = 0.f;
                    if ((unsigned)ih < (unsigned)HH && (unsigned)iw < (unsigned)WW) {
                        size_t ix = pb + (size_t)ih * WW + iw;
                        v1 = base1[ix]; v2 = base2[ix];
                    }
                    s1[r * SW + c] = v1;
                    s2[r * SW + c] = v2;
                }
            }
            __syncthreads();

            // ---- stage B: W-conv, 42 rows x 4 col-quads, f4 per thread ----
            if (tid < HALO_H * 4) {
                const int r = tid >> 2;
                const int cq = (tid & 3) * 4;          // output cols cq..cq+3
                const float* r1 = s1 + r * SW + cq;
                const float* r2 = s2 + r * SW + cq;
                float t1[4]  = {0.f,0.f,0.f,0.f};
                float t2[4]  = {0.f,0.f,0.f,0.f};
                float t11[4] = {0.f,0.f,0.f,0.f};
                float t22[4] = {0.f,0.f,0.f,0.f};
                float t12[4] = {0.f,0.f,0.f,0.f};
#pragma unroll
                for (int ch = 0; ch < 4; ++ch) {       // consume 4 floats at a time
                    f4 a4 = *(const f4*)(r1 + 4 * ch);
                    f4 b4 = *(const f4*)(r2 + 4 * ch);
#pragma unroll
                    for (int ii = 0; ii < 4; ++ii) {
                        const int i = 4 * ch + ii;     // input col offset (need 0..13)
                        if (i > 13) break;
                        float av = a4[ii], bv = b4[ii];
                        float aa = av * av, bb2 = bv * bv, ab = av * bv;
#pragma unroll
                        for (int j = 0; j < 4; ++j) {
                            const int k = i - j;
                            if (k >= 0 && k < KK) {
                                float w = g[k];
                                t1[j]  += w * av;
                                t2[j]  += w * bv;
                                t11[j] += w * aa;
                                t22[j] += w * bb2;
                                t12[j] += w * ab;
                            }
                        }
                    }
                }
                const int tb = r * TS + cq;            // 16B-aligned (TS,cq mult of 4)
                f4 v;
                v[0]=t1[0];  v[1]=t1[1];  v[2]=t1[2];  v[3]=t1[3];  *(f4*)&tmp[0][tb] = v;
                v[0]=t2[0];  v[1]=t2[1];  v[2]=t2[2];  v[3]=t2[3];  *(f4*)&tmp[1][tb] = v;
                v[0]=t11[0]; v[1]=t11[1]; v[2]=t11[2]; v[3]=t11[3]; *(f4*)&tmp[2][tb] = v;
                v[0]=t22[0]; v[1]=t22[1]; v[2]=t22[2]; v[3]=t22[3]; *(f4*)&tmp[3][tb] = v;
                v[0]=t12[0]; v[1]=t12[1]; v[2]=t12[2]; v[3]=t12[3]; *(f4*)&tmp[4][tb] = v;
            }
            __syncthreads();

            // ---- stage C: H-conv (f2 via b64 taps) + D ring scatter ----
            f2 P1 = 0.f, P2 = 0.f, P11 = 0.f, P22 = 0.f, P12 = 0.f;
#pragma unroll
            for (int k = 0; k < KK; ++k) {
                const float w = g[k];
                const int off = (ty + k) * TS + 2 * xc;
                f2 v;
                v = *(const f2*)&tmp[0][off]; P1  += w * v;
                v = *(const f2*)&tmp[1][off]; P2  += w * v;
                v = *(const f2*)&tmp[2][off]; P11 += w * v;
                v = *(const f2*)&tmp[3][off]; P22 += w * v;
                v = *(const f2*)&tmp[4][off]; P12 += w * v;
            }
#pragma unroll
            for (int i = 0; i < KK; ++i) {
                const float w = g[KK - 1 - i];
                a1[i]  += w * P1;
                a2[i]  += w * P2;
                a11[i] += w * P11;
                a22[i] += w * P22;
                a12[i] += w * P12;
            }
        }

        if (p >= 2 * RAD) {   // output plane od0 + p - 10 complete in slot 0
            f2 mu1 = a1[0], mu2 = a2[0];
            f2 m11 = mu1 * mu1, m22 = mu2 * mu2, m12 = mu1 * mu2;
            f2 sg1 = a11[0] - m11, sg2 = a22[0] - m22, sg12 = a12[0] - m12;
            const float C1c = 0.0001f, C2c = 0.0009f;
            f2 num = (2.f * m12 + C1c) * (2.f * sg12 + C2c);
            f2 den = (m11 + m22 + C1c) * (sg1 + sg2 + C2c);
            lsum += num / den;
        }
        // shift ring
#pragma unroll
        for (int i = 0; i < KK - 1; ++i) {
            a1[i] = a1[i+1]; a2[i] = a2[i+1]; a11[i] = a11[i+1];
            a22[i] = a22[i+1]; a12[i] = a12[i+1];
        }
        a1[KK-1]=0.f; a2[KK-1]=0.f; a11[KK-1]=0.f; a22[KK-1]=0.f; a12[KK-1]=0.f;
    }

    // ---- reduction: wave shuffle -> LDS -> one atomic per block ----
    float v = lsum.x + lsum.y;
#pragma unroll
    for (int off = 32; off > 0; off >>= 1)
        v += __shfl_down(v, off, 64);
    if ((tid & 63) == 0) wsum[tid >> 6] = v;
    __syncthreads();
    if (tid == 0) {
        const float inv_n = 1.0f / ((float)BB * DD * HH * WW);
        atomicAdd(out, (wsum[0] + wsum[1] + wsum[2] + wsum[3]) * inv_n);
    }
}

extern "C" void kernel_launch(void* const* d_in, const int* in_sizes, int n_in,
                              void* d_out, int out_size, void* d_ws, size_t ws_size,
                              hipStream_t stream) {
    const float* img1 = (const float*)d_in[0];
    const float* img2 = (const float*)d_in[1];
    float* out = (float*)d_out;

    GaussW gw;
    double gd[KK], sum = 0.0;
    for (int i = 0; i < KK; ++i) {
        double x = (double)(i - KK / 2);
        gd[i] = exp(-(x * x) / (2.0 * 1.5 * 1.5));
        sum += gd[i];
    }
    for (int i = 0; i < KK; ++i) gw.g[i] = (float)(gd[i] / sum);

    hipMemsetAsync(d_out, 0, sizeof(float), stream);

    dim3 grid(10 * 5 * NDCH * BB);   // 1600 blocks
    dim3 block(256);
    hipLaunchKernelGGL(ssim3d_kernel, grid, block, 0, stream,
                       img1, img2, out, gw);
}

// Round 4
// 343.855 us; speedup vs baseline: 1.5949x; 1.5949x over previous
//
#include <hip/hip_runtime.h>
#include <math.h>

typedef float f2 __attribute__((ext_vector_type(2)));
typedef float f4 __attribute__((ext_vector_type(4)));

#define DD 160
#define HH 160
#define WW 160
#define BB 4
#define KK 11
#define RAD 5
#define TH 16
#define TW 16
#define DCH 32
#define NPLANES (DCH + 2 * RAD)   // 42
#define NDCH (DD / DCH)           // 5
#define HALO_H (TH + 2 * RAD)     // 26
#define TS 16                     // tmp row stride: uniform banks for this wave pattern

struct GaussW { float g[KK]; };

__global__ __launch_bounds__(128, 3)
void ssim3d_kernel(const float* __restrict__ img1,
                   const float* __restrict__ img2,
                   float* __restrict__ out, GaussW gw)
{
    // double-buffered W-conv results: one barrier per plane
    __shared__ float tmp[2][5][HALO_H * TS];   // 16.6 KB
    __shared__ float wsum[2];

    const int tid = threadIdx.x;        // 128 threads = 2 waves
    // phase-2 mapping: 16 rows x 8 col-pairs
    const int xc = tid & 7;             // cols 2xc, 2xc+1
    const int ty = tid >> 3;            // 0..15
    // phase-1 mapping: 26 rows x 4 quads (104 active)
    const int p1r = tid >> 2;           // 0..31 (<26 active)
    const int p1q = tid & 3;            // quad 0..3 -> tmp cols 4q..4q+3

    const int blk = blockIdx.x;
    const int bw = blk % 10;
    const int bh = (blk / 10) % 10;
    const int bd = (blk / 100) % NDCH;
    const int bb = blk / (100 * NDCH);

    const int oh0 = bh * TH, ow0 = bw * TW, od0 = bd * DCH;
    const float* base1 = img1 + (size_t)bb * DD * HH * WW;
    const float* base2 = img2 + (size_t)bb * DD * HH * WW;

    float g[KK];
#pragma unroll
    for (int i = 0; i < KK; ++i) g[i] = gw.g[i];

    // D-ring (f2 = 2 W-cols): slot i -> output plane emitted i planes from now
    f2 a1[KK], a2[KK], a11[KK], a22[KK], a12[KK];
#pragma unroll
    for (int i = 0; i < KK; ++i) { a1[i]=0.f; a2[i]=0.f; a11[i]=0.f; a22[i]=0.f; a12[i]=0.f; }

    f2 lsum = 0.f;

    // phase-1 per-thread constants
    const int gh = oh0 - RAD + p1r;                       // img row
    const bool p1act = (p1r < HALO_H);
    const bool rowok = p1act && ((unsigned)gh < (unsigned)HH);
    const int gc0 = ow0 + 4 * p1q - 8;                    // first loaded img col (aligned)
    const size_t rowoff = (size_t)((unsigned)gh < (unsigned)HH ? gh : 0) * WW;

    for (int p = 0; p < NPLANES; ++p) {
        const int d = od0 - RAD + p;
        const bool dval = ((unsigned)d < (unsigned)DD);   // block-uniform
        const int buf = p & 1;

        if (dval) {
            // ---- phase 1: W-conv of 5 stats straight from global regs ----
            if (p1act) {
                float t1[4]  = {0.f,0.f,0.f,0.f};
                float t2[4]  = {0.f,0.f,0.f,0.f};
                float t11[4] = {0.f,0.f,0.f,0.f};
                float t22[4] = {0.f,0.f,0.f,0.f};
                float t12[4] = {0.f,0.f,0.f,0.f};
                const size_t pb = (size_t)d * HH * WW + rowoff;
#pragma unroll
                for (int j = 0; j < 5; ++j) {
                    const int gc = gc0 + 4 * j;
                    f4 av4 = {0.f,0.f,0.f,0.f};
                    f4 bv4 = {0.f,0.f,0.f,0.f};
                    if (rowok && gc >= 0 && gc <= WW - 4) {
                        av4 = *(const f4*)(base1 + pb + gc);
                        bv4 = *(const f4*)(base2 + pb + gc);
                    }
#pragma unroll
                    for (int ii = 0; ii < 4; ++ii) {
                        const int i = 4 * j + ii;          // local col 0..19; need 3..16
                        if (i < 3 || i > 16) continue;
                        const float av = av4[ii], bv = bv4[ii];
                        const float aa = av * av, bb2 = bv * bv, ab = av * bv;
#pragma unroll
                        for (int m = 0; m < 4; ++m) {
                            const int k = i - m - 3;       // tap index
                            if (k >= 0 && k < KK) {
                                const float w = g[k];
                                t1[m]  += w * av;
                                t2[m]  += w * bv;
                                t11[m] += w * aa;
                                t22[m] += w * bb2;
                                t12[m] += w * ab;
                            }
                        }
                    }
                }
                const int tb = p1r * TS + 4 * p1q;         // 16B-aligned
                f4 v;
                v[0]=t1[0];  v[1]=t1[1];  v[2]=t1[2];  v[3]=t1[3];  *(f4*)&tmp[buf][0][tb] = v;
                v[0]=t2[0];  v[1]=t2[1];  v[2]=t2[2];  v[3]=t2[3];  *(f4*)&tmp[buf][1][tb] = v;
                v[0]=t11[0]; v[1]=t11[1]; v[2]=t11[2]; v[3]=t11[3]; *(f4*)&tmp[buf][2][tb] = v;
                v[0]=t22[0]; v[1]=t22[1]; v[2]=t22[2]; v[3]=t22[3]; *(f4*)&tmp[buf][3][tb] = v;
                v[0]=t12[0]; v[1]=t12[1]; v[2]=t12[2]; v[3]=t12[3]; *(f4*)&tmp[buf][4][tb] = v;
            }
            __syncthreads();   // the only barrier per plane (dbuf covers WAR)

            // ---- phase 2: H-conv (f2 b64 taps, conflict-free) + D ring scatter ----
            f2 P1 = 0.f, P2 = 0.f, P11 = 0.f, P22 = 0.f, P12 = 0.f;
#pragma unroll
            for (int k = 0; k < KK; ++k) {
                const float w = g[k];
                const int off = (ty + k) * TS + 2 * xc;
                f2 v;
                v = *(const f2*)&tmp[buf][0][off]; P1  += w * v;
                v = *(const f2*)&tmp[buf][1][off]; P2  += w * v;
                v = *(const f2*)&tmp[buf][2][off]; P11 += w * v;
                v = *(const f2*)&tmp[buf][3][off]; P22 += w * v;
                v = *(const f2*)&tmp[buf][4][off]; P12 += w * v;
            }
#pragma unroll
            for (int i = 0; i < KK; ++i) {
                const float w = g[KK - 1 - i];
                a1[i]  += w * P1;
                a2[i]  += w * P2;
                a11[i] += w * P11;
                a22[i] += w * P22;
                a12[i] += w * P12;
            }
        }

        if (p >= 2 * RAD) {   // output plane od0 + p - 10 complete in slot 0
            f2 mu1 = a1[0], mu2 = a2[0];
            f2 m11 = mu1 * mu1, m22 = mu2 * mu2, m12 = mu1 * mu2;
            f2 sg1 = a11[0] - m11, sg2 = a22[0] - m22, sg12 = a12[0] - m12;
            const float C1c = 0.0001f, C2c = 0.0009f;
            f2 num = (2.f * m12 + C1c) * (2.f * sg12 + C2c);
            f2 den = (m11 + m22 + C1c) * (sg1 + sg2 + C2c);
            lsum += num / den;
        }
        // shift ring (f2 moves -> v_pk_mov)
#pragma unroll
        for (int i = 0; i < KK - 1; ++i) {
            a1[i] = a1[i+1]; a2[i] = a2[i+1]; a11[i] = a11[i+1];
            a22[i] = a22[i+1]; a12[i] = a12[i+1];
        }
        a1[KK-1]=0.f; a2[KK-1]=0.f; a11[KK-1]=0.f; a22[KK-1]=0.f; a12[KK-1]=0.f;
    }

    // ---- reduction: wave shuffle -> LDS -> one atomic per block ----
    float v = lsum.x + lsum.y;
#pragma unroll
    for (int off = 32; off > 0; off >>= 1)
        v += __shfl_down(v, off, 64);
    if ((tid & 63) == 0) wsum[tid >> 6] = v;
    __syncthreads();
    if (tid == 0) {
        const float inv_n = 1.0f / ((float)BB * DD * HH * WW);
        atomicAdd(out, (wsum[0] + wsum[1]) * inv_n);
    }
}

extern "C" void kernel_launch(void* const* d_in, const int* in_sizes, int n_in,
                              void* d_out, int out_size, void* d_ws, size_t ws_size,
                              hipStream_t stream) {
    const float* img1 = (const float*)d_in[0];
    const float* img2 = (const float*)d_in[1];
    float* out = (float*)d_out;

    GaussW gw;
    double gd[KK], sum = 0.0;
    for (int i = 0; i < KK; ++i) {
        double x = (double)(i - KK / 2);
        gd[i] = exp(-(x * x) / (2.0 * 1.5 * 1.5));
        sum += gd[i];
    }
    for (int i = 0; i < KK; ++i) gw.g[i] = (float)(gd[i] / sum);

    hipMemsetAsync(d_out, 0, sizeof(float), stream);

    dim3 grid(10 * 10 * NDCH * BB);   // 2000 blocks
    dim3 block(128);
    hipLaunchKernelGGL(ssim3d_kernel, grid, block, 0, stream,
                       img1, img2, out, gw);
}

// Round 5
// 335.039 us; speedup vs baseline: 1.6369x; 1.0263x over previous
//
#include <hip/hip_runtime.h>
#include <math.h>
#include <type_traits>

typedef float f2 __attribute__((ext_vector_type(2)));
typedef float f4 __attribute__((ext_vector_type(4)));

#define DD 160
#define HH 160
#define WW 160
#define BB 4
#define KK 11
#define RAD 5
#define TH 16
#define TW 16
#define DCH 32
#define NPLANES (DCH + 2 * RAD)   // 42 (loop padded to 44 = 4*11)
#define NDCH (DD / DCH)           // 5
#define HALO_H (TH + 2 * RAD)     // 26
#define TS 16                     // tmp row stride: uniform banks (r4: 0 conflicts)
#define STAT (HALO_H * TS)        // 416 floats per stat plane

struct GaussW { float g[KK]; };

__global__ __launch_bounds__(128, 2)
void ssim3d_kernel(const float* __restrict__ img1,
                   const float* __restrict__ img2,
                   float* __restrict__ out, GaussW gw)
{
    __shared__ float tmpA[5 * STAT];   // double buffer via pointer swap
    __shared__ float tmpB[5 * STAT];
    __shared__ float wsum[2];

    const int tid = threadIdx.x;        // 128 threads = 2 waves
    // phase-2 mapping: 16 rows x 8 col-pairs
    const int xc = tid & 7;             // cols 2xc, 2xc+1
    const int ty = tid >> 3;            // 0..15
    // phase-1 mapping: 26 rows x 4 quads (104 active)
    const int p1r = tid >> 2;
    const int p1q = tid & 3;

    const int blk = blockIdx.x;
    const int bw = blk % 10;
    const int bh = (blk / 10) % 10;
    const int bd = (blk / 100) % NDCH;
    const int bb = blk / (100 * NDCH);

    const int oh0 = bh * TH, ow0 = bw * TW, od0 = bd * DCH;
    const float* base1 = img1 + (size_t)bb * DD * HH * WW;
    const float* base2 = img2 + (size_t)bb * DD * HH * WW;

    float g[KK];
#pragma unroll
    for (int i = 0; i < KK; ++i) g[i] = gw.g[i];

    // static D-ring: slot s holds output q with q % 11 == s (f2 = 2 W-cols)
    f2 a1[KK], a2[KK], a11[KK], a22[KK], a12[KK];
#pragma unroll
    for (int i = 0; i < KK; ++i) { a1[i]=0.f; a2[i]=0.f; a11[i]=0.f; a22[i]=0.f; a12[i]=0.f; }

    f2 lsum = 0.f;

    // phase-1 per-thread constants
    const int gh = oh0 - RAD + p1r;
    const bool p1act = (p1r < HALO_H);
    const bool rowok = p1act && ((unsigned)gh < (unsigned)HH);
    const int gc0 = ow0 + 4 * p1q - 8;                    // first loaded col (16B aligned)
    const size_t rowoff = (size_t)((unsigned)gh < (unsigned)HH ? gh : 0) * WW;

    // prefetch registers for the next plane's 20 cols per thread
    f4 pa[5], pb[5];
#pragma unroll
    for (int j = 0; j < 5; ++j) { pa[j] = (f4)0.f; pb[j] = (f4)0.f; }

    float* twr = tmpA;   // buffer written (and read) this plane
    float* trd = tmpB;   // buffer of the previous plane

    // preamble: prefetch plane p=0 if valid
    {
        const int dn = od0 - RAD;
        if (p1act && (unsigned)dn < (unsigned)DD) {
            const size_t pbv = (size_t)dn * (HH * WW) + rowoff;
#pragma unroll
            for (int j = 0; j < 5; ++j) {
                const int gc = gc0 + 4 * j;
                f4 za = (f4)0.f, zb = (f4)0.f;
                if (rowok && gc >= 0 && gc <= WW - 4) {
                    za = *(const f4*)(base1 + pbv + gc);
                    zb = *(const f4*)(base2 + pbv + gc);
                }
                pa[j] = za; pb[j] = zb;
            }
        }
    }

    int pcbase = 0;
    auto body = [&](auto uc) {
        constexpr int U = decltype(uc)::value;
        const int p = pcbase + U;
        const int d = od0 - RAD + p;
        const bool dval = (p < NPLANES) && ((unsigned)d < (unsigned)DD);  // block-uniform

        // ---- phase 1: W-conv of 5 stats from prefetched regs ----
        if (dval && p1act) {
            float t1[4]  = {0.f,0.f,0.f,0.f};
            float t2[4]  = {0.f,0.f,0.f,0.f};
            float t11[4] = {0.f,0.f,0.f,0.f};
            float t22[4] = {0.f,0.f,0.f,0.f};
            float t12[4] = {0.f,0.f,0.f,0.f};
#pragma unroll
            for (int j = 0; j < 5; ++j) {
#pragma unroll
                for (int ii = 0; ii < 4; ++ii) {
                    const int i = 4 * j + ii;          // local col 0..19; need 3..16
                    if (i < 3 || i > 16) continue;
                    const float av = pa[j][ii], bv = pb[j][ii];
                    const float aa = av * av, bb2 = bv * bv, ab = av * bv;
#pragma unroll
                    for (int m = 0; m < 4; ++m) {
                        const int k = i - m - 3;       // tap index
                        if (k >= 0 && k < KK) {
                            const float w = g[k];
                            t1[m]  += w * av;
                            t2[m]  += w * bv;
                            t11[m] += w * aa;
                            t22[m] += w * bb2;
                            t12[m] += w * ab;
                        }
                    }
                }
            }
            float* tw = twr + p1r * TS + 4 * p1q;      // 16B-aligned
            f4 v;
            v[0]=t1[0];  v[1]=t1[1];  v[2]=t1[2];  v[3]=t1[3];  *(f4*)(tw + 0*STAT) = v;
            v[0]=t2[0];  v[1]=t2[1];  v[2]=t2[2];  v[3]=t2[3];  *(f4*)(tw + 1*STAT) = v;
            v[0]=t11[0]; v[1]=t11[1]; v[2]=t11[2]; v[3]=t11[3]; *(f4*)(tw + 2*STAT) = v;
            v[0]=t22[0]; v[1]=t22[1]; v[2]=t22[2]; v[3]=t22[3]; *(f4*)(tw + 3*STAT) = v;
            v[0]=t12[0]; v[1]=t12[1]; v[2]=t12[2]; v[3]=t12[3]; *(f4*)(tw + 4*STAT) = v;
        }

        // ---- prefetch plane p+1 (completes behind the barrier + phase 2) ----
        {
            const int pn = p + 1;
            const int dn = od0 - RAD + pn;
            if (p1act && (pn < NPLANES) && ((unsigned)dn < (unsigned)DD)) {
                const size_t pbv = (size_t)dn * (HH * WW) + rowoff;
#pragma unroll
                for (int j = 0; j < 5; ++j) {
                    const int gc = gc0 + 4 * j;
                    f4 za = (f4)0.f, zb = (f4)0.f;
                    if (rowok && gc >= 0 && gc <= WW - 4) {
                        za = *(const f4*)(base1 + pbv + gc);
                        zb = *(const f4*)(base2 + pbv + gc);
                    }
                    pa[j] = za; pb[j] = zb;
                }
            }
        }

        // ---- phase 2: H-conv (f2 b64, conflict-free) + static-slot D scatter ----
        if (dval) {
            __syncthreads();   // only barrier per plane (dbuf pointer swap covers WAR)
            f2 P1 = 0.f, P2 = 0.f, P11 = 0.f, P22 = 0.f, P12 = 0.f;
            const float* tb = twr + (ty * TS + 2 * xc);
#pragma unroll
            for (int k = 0; k < KK; ++k) {
                const float w = g[k];
                const int o = k * TS;
                P1  += w * *(const f2*)(tb + 0*STAT + o);
                P2  += w * *(const f2*)(tb + 1*STAT + o);
                P11 += w * *(const f2*)(tb + 2*STAT + o);
                P22 += w * *(const f2*)(tb + 3*STAT + o);
                P12 += w * *(const f2*)(tb + 4*STAT + o);
            }
#pragma unroll
            for (int t = 0; t < KK; ++t) {
                constexpr int base = U + 22;
                const int s = (base - t) % 11;         // folds: U, t compile-time
                const float w = g[t];
                a1[s]  += w * P1;
                a2[s]  += w * P2;
                a11[s] += w * P11;
                a22[s] += w * P22;
                a12[s] += w * P12;
            }
        }

        // ---- emit output q = p-10 from fixed slot (U+1)%11, then zero it ----
        constexpr int e = (U + 1) % 11;
        if (p >= 2 * RAD && p < NPLANES) {
            f2 mu1 = a1[e], mu2 = a2[e];
            f2 m11 = mu1 * mu1, m22 = mu2 * mu2, m12 = mu1 * mu2;
            f2 sg1 = a11[e] - m11, sg2 = a22[e] - m22, sg12 = a12[e] - m12;
            const float C1c = 0.0001f, C2c = 0.0009f;
            f2 num = (2.f * m12 + C1c) * (2.f * sg12 + C2c);
            f2 den = (m11 + m22 + C1c) * (sg1 + sg2 + C2c);
            lsum += num / den;
        }
        a1[e] = 0.f; a2[e] = 0.f; a11[e] = 0.f; a22[e] = 0.f; a12[e] = 0.f;

        // swap double buffers
        float* t = twr; twr = trd; trd = t;
    };

    for (pcbase = 0; pcbase < 44; pcbase += 11) {
        body(std::integral_constant<int, 0>{});
        body(std::integral_constant<int, 1>{});
        body(std::integral_constant<int, 2>{});
        body(std::integral_constant<int, 3>{});
        body(std::integral_constant<int, 4>{});
        body(std::integral_constant<int, 5>{});
        body(std::integral_constant<int, 6>{});
        body(std::integral_constant<int, 7>{});
        body(std::integral_constant<int, 8>{});
        body(std::integral_constant<int, 9>{});
        body(std::integral_constant<int, 10>{});
    }

    // ---- reduction: wave shuffle -> LDS -> one atomic per block ----
    float v = lsum.x + lsum.y;
#pragma unroll
    for (int off = 32; off > 0; off >>= 1)
        v += __shfl_down(v, off, 64);
    if ((tid & 63) == 0) wsum[tid >> 6] = v;
    __syncthreads();
    if (tid == 0) {
        const float inv_n = 1.0f / ((float)BB * DD * HH * WW);
        atomicAdd(out, (wsum[0] + wsum[1]) * inv_n);
    }
}

extern "C" void kernel_launch(void* const* d_in, const int* in_sizes, int n_in,
                              void* d_out, int out_size, void* d_ws, size_t ws_size,
                              hipStream_t stream) {
    const float* img1 = (const float*)d_in[0];
    const float* img2 = (const float*)d_in[1];
    float* out = (float*)d_out;

    GaussW gw;
    double gd[KK], sum = 0.0;
    for (int i = 0; i < KK; ++i) {
        double x = (double)(i - KK / 2);
        gd[i] = exp(-(x * x) / (2.0 * 1.5 * 1.5));
        sum += gd[i];
    }
    for (int i = 0; i < KK; ++i) gw.g[i] = (float)(gd[i] / sum);

    hipMemsetAsync(d_out, 0, sizeof(float), stream);

    dim3 grid(10 * 10 * NDCH * BB);   // 2000 blocks
    dim3 block(128);
    hipLaunchKernelGGL(ssim3d_kernel, grid, block, 0, stream,
                       img1, img2, out, gw);
}